// Round 9
// baseline (178.524 us; speedup 1.0000x reference)
//
#include <hip/hip_runtime.h>
#include <math.h>

#define T_LEN      24000
#define TS         12000         // samples per half
#define W_LEN      81
#define HALF_W     40
#define NK         21
#define MAXORD     10
#define NIMG_TOTAL 1561          // |{k in [-10,10]^3 : |kx|+|ky|+|kz| <= 10}|
#define NROUNDS    25            // ceil(1561/64)
#define FS_F       48000.0f
#define C_F        343.0f
#define FS_OVER_C  (48000.0f / 343.0f)
#define PI_F       3.14159265358979323846f
#define INV_4PI_F  0.07957747154594767f
#define LOG2_BETA  (-0.15200309344504997f)   // log2(0.9)
#define NEG_SLOPE  0.01f
#define NTHREADS   512
#define NWAVES     8

// ---- compile-time table of valid image triples ----
// entry: (order << 15) | (kxi << 10) | (kyi << 5) | kzi
struct Table { unsigned int e[NROUNDS * 64]; };   // padded; entries >= NIMG_TOTAL are dups of last

constexpr Table make_table() {
    Table t{};
    int n = 0;
    for (int kx = 0; kx < NK; ++kx)
        for (int ky = 0; ky < NK; ++ky)
            for (int kz = 0; kz < NK; ++kz) {
                int ax = kx >= MAXORD ? kx - MAXORD : MAXORD - kx;
                int ay = ky >= MAXORD ? ky - MAXORD : MAXORD - ky;
                int az = kz >= MAXORD ? kz - MAXORD : MAXORD - kz;
                int order = ax + ay + az;
                if (order <= MAXORD)
                    t.e[n++] = (unsigned)((order << 15) | (kx << 10) | (ky << 5) | kz);
            }
    for (int i = n; i < NROUNDS * 64; ++i) t.e[i] = t.e[n - 1];  // padding (masked off)
    return t;
}
__constant__ Table g_tbl = make_table();

// One drained image: broadcast (aU, dU); pure-register tap math.
#define PROCESS(aU, dU)                                                        \
    do {                                                                       \
        float t0b  = floorf(dU);                                              \
        float frac = dU - t0b;                                                \
        float sp   = __sinf(PI_F * frac);                                     \
        float pv   = sg * sp;                                                 \
        int   idx  = (int)t0b - HALF_W + lane - lo;                           \
        float x1p  = c1p - PI_F * frac;                                       \
        float sv1  = (x1p == 0.0f) ? 1.0f : pv * __builtin_amdgcn_rcpf(x1p);  \
        if ((unsigned)idx < (unsigned)TS)                                     \
            atomicAdd(&rir[idx], (aU) * sv1 * hw1);                           \
        if (lane < 17) {                                                      \
            int   idx2 = idx + 64;                                            \
            float sv2  = pv * __builtin_amdgcn_rcpf(x1p + 64.0f * PI_F);      \
            if ((unsigned)idx2 < (unsigned)TS)                                \
                atomicAdd(&rir[idx2], (aU) * sv2 * hw2);                      \
        }                                                                      \
    } while (0)

__global__ __launch_bounds__(NTHREADS)
void rir_min_kernel(const float* __restrict__ g_in,
                    const float* __restrict__ W1, const float* __restrict__ b1,
                    const float* __restrict__ W2, const float* __restrict__ b2,
                    const float* __restrict__ W3, const float* __restrict__ b3,
                    float* __restrict__ out_rir, float* __restrict__ out_origin)
{
    __shared__ __align__(16) float rir[TS];          // 48000 B
    __shared__ float dsq[3 * NK];                    // (img - mic)^2 per axis
    __shared__ float h1[30], h2[20], zb[9], sm_in[22], rms[9];

    const int tid  = threadIdx.x;
    const int lane = tid & 63;
    const int wave = tid >> 6;
    const int half = blockIdx.x;
    const int b    = blockIdx.y;
    const int lo   = half * TS;

    // ---- batch this wave's g_tbl loads up-front (one latency hit) ----
    const int r0 = wave, r1 = wave + 8, r2 = wave + 16, r3 = wave + 24;
    const unsigned e0 = g_tbl.e[r0 * 64 + lane];
    const unsigned e1 = g_tbl.e[r1 * 64 + lane];
    const unsigned e2 = g_tbl.e[r2 * 64 + lane];
    const unsigned e3 = (r3 < NROUNDS) ? g_tbl.e[r3 * 64 + lane] : 0u;

    // ---- per-lane loop invariants (registers) ----
    const float c1p = PI_F * (float)(lane - HALF_W);
    const float hw1 = 0.5f - 0.5f * __cosf((float)lane * (2.0f * PI_F / 80.0f));
    const float hw2 = 0.5f - 0.5f * __cosf((float)(lane + 64) * (2.0f * PI_F / 80.0f));
    const float sg  = (lane & 1) ? 1.0f : -1.0f;   // sin(pi(n-frac)) = -(-1)^n sin(pi frac)

    // ---- zero the half-row accumulator ----
    float4* rir4 = (float4*)rir;
    #pragma unroll
    for (int i = tid; i < TS / 4; i += NTHREADS)
        rir4[i] = make_float4(0.f, 0.f, 0.f, 0.f);

    // ---- wave 0: input row, MLP, geometry (in-wave LDS ordering) ----
    if (tid < 64) {
        if (tid < 22) sm_in[tid] = g_in[b * 22 + tid];
        if (tid < 30) {
            float a = b1[tid];
            const float* w = W1 + tid * 22;
            #pragma unroll
            for (int i = 0; i < 22; ++i) a += sm_in[i] * w[i];
            h1[tid] = (a >= 0.0f) ? a : NEG_SLOPE * a;
        }
        if (tid < 20) {
            float a = b2[tid];
            const float* w = W2 + tid * 30;
            #pragma unroll
            for (int i = 0; i < 30; ++i) a += h1[i] * w[i];
            h2[tid] = (a >= 0.0f) ? a : NEG_SLOPE * a;
        }
        if (tid < 9) {
            float a = b3[tid];
            const float* w = W3 + tid * 20;
            #pragma unroll
            for (int i = 0; i < 20; ++i) a += h2[i] * w[i];
            zb[tid] = 1.0f / (1.0f + __expf(-a));
        }
        if (tid < 3) {
            float room = zb[tid] * 20.0f;
            rms[tid]     = room;
            rms[3 + tid] = zb[3 + tid] * room;   // mic
            rms[6 + tid] = zb[6 + tid] * room;   // src
        }
        if (tid == 0 && half == 0) {
            float dx = rms[3] - rms[6], dy = rms[4] - rms[7], dz = rms[5] - rms[8];
            out_origin[b] = 40.0f + FS_F * sqrtf(dx * dx + dy * dy + dz * dz) / C_F;
        }
        if (tid < 3 * NK) {
            int a  = tid / NK;
            int kk = (tid - a * NK) - MAXORD;
            float L = rms[a], src = rms[6 + a];
            float img = ((kk & 1) == 0) ? (float)kk * L + src : (float)(kk + 1) * L - src;
            float diff = img - rms[3 + a];
            dsq[tid] = diff * diff;
        }
    }
    __syncthreads();

    // ---- rounds: lane computes its image's params; wave drains hits via ballot ----
    const float lof = (float)(lo - HALF_W);          // t0 >= lo-40
    const float hif = (float)(lo + TS - 1 + HALF_W); // t0 <= lo+TS-1+40
    const unsigned evs[4] = {e0, e1, e2, e3};
    const int      rs[4]  = {r0, r1, r2, r3};

    #pragma unroll
    for (int q = 0; q < 4; ++q) {
        if (rs[q] >= NROUNDS) break;
        const unsigned e = evs[q];
        const bool live  = (rs[q] * 64 + lane) < NIMG_TOTAL;
        int kzi = e & 31, kyi = (e >> 5) & 31, kxi = (e >> 10) & 31, order = (int)(e >> 15);
        float d    = sqrtf(dsq[kxi] + dsq[NK + kyi] + dsq[2 * NK + kzi]);
        float dlyv = 40.0f + d * FS_OVER_C;
        float t0f  = floorf(dlyv);
        float ampv = exp2f((float)order * LOG2_BETA) * INV_4PI_F
                     * __builtin_amdgcn_rcpf(fmaxf(d, 0.001f));
        bool hit = live && (t0f >= lof) && (t0f <= hif);

        unsigned long long mask = __ballot(hit);
        while (mask) {
            int l0 = __builtin_ctzll(mask); mask &= mask - 1;
            bool have1 = (mask != 0);
            int l1 = have1 ? __builtin_ctzll(mask) : l0;
            if (have1) mask &= mask - 1;

            float a0 = __shfl(ampv, l0), d0 = __shfl(dlyv, l0);
            float a1 = __shfl(ampv, l1), d1 = __shfl(dlyv, l1);
            PROCESS(a0, d0);
            if (have1) PROCESS(a1, d1);
        }
    }
    __syncthreads();

    // ---- coalesced float4 writeback of this half ----
    float4* out4 = (float4*)(out_rir + (size_t)b * T_LEN + lo);
    #pragma unroll
    for (int i = tid; i < TS / 4; i += NTHREADS) out4[i] = rir4[i];
}

extern "C" void kernel_launch(void* const* d_in, const int* in_sizes, int n_in,
                              void* d_out, int out_size, void* d_ws, size_t ws_size,
                              hipStream_t stream) {
    const float* g_in = (const float*)d_in[0];
    const float* W1   = (const float*)d_in[1];
    const float* b1   = (const float*)d_in[2];
    const float* W2   = (const float*)d_in[3];
    const float* b2   = (const float*)d_in[4];
    const float* W3   = (const float*)d_in[5];
    const float* b3   = (const float*)d_in[6];

    const int B = in_sizes[0] / 22;

    float* out_rir    = (float*)d_out;
    float* out_origin = out_rir + (size_t)B * T_LEN;

    dim3 grid(2, B);   // (half, row) -> 256 workgroups, one per CU
    rir_min_kernel<<<grid, NTHREADS, 0, stream>>>(
        g_in, W1, b1, W2, b2, W3, b3, out_rir, out_origin);
}

// Round 10
// 119.571 us; speedup vs baseline: 1.4930x; 1.4930x over previous
//
#include <hip/hip_runtime.h>
#include <math.h>

#define T_LEN      24000
#define TS         448           // samples per slice (64 lanes x 7)
#define NSLICE     54            // 54*448 = 24192 >= 24000 (last slice: 256 valid)
#define W_LEN      81
#define HALF_W     40
#define NK         21
#define MAXORD     10
#define NIMG_TOTAL 1561          // |{k in [-10,10]^3 : |kx|+|ky|+|kz| <= 10}|
#define NROUNDS    25            // ceil(1561/64)
#define FS_F       48000.0f
#define C_F        343.0f
#define FS_OVER_C  (48000.0f / 343.0f)
#define PI_F       3.14159265358979323846f
#define INV_4PI_F  0.07957747154594767f
#define LOG2_BETA  (-0.15200309344504997f)   // log2(0.9)
#define NEG_SLOPE  0.01f

// ---- compile-time table of valid image triples ----
// entry: (order << 15) | (kxi << 10) | (kyi << 5) | kzi
struct Table { unsigned int e[NROUNDS * 64]; };   // padded; pad entries masked off

constexpr Table make_table() {
    Table t{};
    int n = 0;
    for (int kx = 0; kx < NK; ++kx)
        for (int ky = 0; ky < NK; ++ky)
            for (int kz = 0; kz < NK; ++kz) {
                int ax = kx >= MAXORD ? kx - MAXORD : MAXORD - kx;
                int ay = ky >= MAXORD ? ky - MAXORD : MAXORD - ky;
                int az = kz >= MAXORD ? kz - MAXORD : MAXORD - kz;
                int order = ax + ay + az;
                if (order <= MAXORD)
                    t.e[n++] = (unsigned)((order << 15) | (kx << 10) | (ky << 5) | kz);
            }
    for (int i = n; i < NROUNDS * 64; ++i) t.e[i] = t.e[n - 1];
    return t;
}
__constant__ Table g_tbl = make_table();

// One drained image: broadcast (aU, dU); pure-register tap math, 2 ds_add max.
#define PROCESS(aU, dU)                                                        \
    do {                                                                       \
        float t0b  = floorf(dU);                                              \
        float frac = dU - t0b;                                                \
        float sp   = __sinf(PI_F * frac);                                     \
        float pv   = sg * sp;                                                 \
        int   idx  = (int)t0b - HALF_W + lane - lo;                           \
        float x1p  = c1p - PI_F * frac;                                       \
        float sv1  = (x1p == 0.0f) ? 1.0f : pv * __builtin_amdgcn_rcpf(x1p);  \
        if ((unsigned)idx < (unsigned)nout)                                   \
            atomicAdd(&rir[idx], (aU) * sv1 * hw1);                           \
        if (lane < 17) {                                                      \
            int idx2 = idx + 64;                                              \
            float sv2 = pv * __builtin_amdgcn_rcpf(x1p + 64.0f * PI_F);       \
            if ((unsigned)idx2 < (unsigned)nout)                              \
                atomicAdd(&rir[idx2], (aU) * sv2 * hw2);                      \
        }                                                                      \
    } while (0)

__global__ __launch_bounds__(64)
void rir_wave_kernel(const float* __restrict__ g_in,
                     const float* __restrict__ W1, const float* __restrict__ b1,
                     const float* __restrict__ W2, const float* __restrict__ b2,
                     const float* __restrict__ W3, const float* __restrict__ b3,
                     float* __restrict__ out_rir, float* __restrict__ out_origin)
{
    // Single-wave block: all LDS producer->consumer pairs are same-wave DS ops
    // (in-order per wave), so NO __syncthreads anywhere.
    __shared__ __align__(16) float rir[TS];          // 1792 B
    __shared__ float dsq[3 * NK];                    // (img - mic)^2 per axis
    __shared__ float h1[30], h2[20], zb[9], sm_in[22], rms[9];

    const int lane = threadIdx.x;
    const int s    = blockIdx.x;
    const int b    = blockIdx.y;
    const int lo   = s * TS;
    const int nout = min(TS, T_LEN - lo);    // 448, or 256 for the last slice

    // ---- zero the slice accumulator (112 float4) ----
    float4* rir4 = (float4*)rir;
    rir4[lane] = make_float4(0.f, 0.f, 0.f, 0.f);
    if (lane < TS / 4 - 64) rir4[64 + lane] = make_float4(0.f, 0.f, 0.f, 0.f);

    // ---- per-lane loop invariants ----
    const float c1p = PI_F * (float)(lane - HALF_W);
    const float hw1 = 0.5f - 0.5f * __cosf((float)lane * (2.0f * PI_F / 80.0f));
    const float hw2 = 0.5f - 0.5f * __cosf((float)(lane + 64) * (2.0f * PI_F / 80.0f));
    const float sg  = (lane & 1) ? 1.0f : -1.0f;   // sin(pi(n-frac)) = -(-1)^n sin(pi frac)

    // ---- MLP + geometry (wave-local, in-order DS) ----
    if (lane < 22) sm_in[lane] = g_in[b * 22 + lane];
    if (lane < 30) {
        float a = b1[lane];
        const float* w = W1 + lane * 22;
        #pragma unroll
        for (int i = 0; i < 22; ++i) a += sm_in[i] * w[i];
        h1[lane] = (a >= 0.0f) ? a : NEG_SLOPE * a;
    }
    if (lane < 20) {
        float a = b2[lane];
        const float* w = W2 + lane * 30;
        #pragma unroll
        for (int i = 0; i < 30; ++i) a += h1[i] * w[i];
        h2[lane] = (a >= 0.0f) ? a : NEG_SLOPE * a;
    }
    if (lane < 9) {
        float a = b3[lane];
        const float* w = W3 + lane * 20;
        #pragma unroll
        for (int i = 0; i < 20; ++i) a += h2[i] * w[i];
        zb[lane] = 1.0f / (1.0f + __expf(-a));
    }
    if (lane < 3) {
        float room = zb[lane] * 20.0f;
        rms[lane]     = room;
        rms[3 + lane] = zb[3 + lane] * room;   // mic
        rms[6 + lane] = zb[6 + lane] * room;   // src
    }
    if (lane == 0 && s == 0) {
        float dx = rms[3] - rms[6], dy = rms[4] - rms[7], dz = rms[5] - rms[8];
        out_origin[b] = 40.0f + FS_F * sqrtf(dx * dx + dy * dy + dz * dz) / C_F;
    }
    if (lane < 3 * NK) {
        int a  = lane / NK;
        int kk = (lane - a * NK) - MAXORD;
        float L = rms[a], src = rms[6 + a];
        float img = ((kk & 1) == 0) ? (float)kk * L + src : (float)(kk + 1) * L - src;
        float diff = img - rms[3 + a];
        dsq[lane] = diff * diff;
    }

    // ---- 25 rounds: lane-parallel params; ballot dual-drain; no barriers ----
    const float lof = (float)(lo - HALF_W);            // t0 >= lo-40
    const float hif = (float)(lo + nout - 1 + HALF_W); // t0 <= lo+nout-1+40

    for (int r = 0; r < NROUNDS; ++r) {
        unsigned e = g_tbl.e[r * 64 + lane];
        bool live  = (r * 64 + lane) < NIMG_TOTAL;
        int kzi = e & 31, kyi = (e >> 5) & 31, kxi = (e >> 10) & 31, order = (int)(e >> 15);
        float d    = sqrtf(dsq[kxi] + dsq[NK + kyi] + dsq[2 * NK + kzi]);
        float dlyv = 40.0f + d * FS_OVER_C;
        float t0f  = floorf(dlyv);
        float ampv = exp2f((float)order * LOG2_BETA) * INV_4PI_F
                     * __builtin_amdgcn_rcpf(fmaxf(d, 0.001f));
        bool hit = live && (t0f >= lof) && (t0f <= hif);

        unsigned long long mask = __ballot(hit);
        while (mask) {
            int l0 = __builtin_ctzll(mask); mask &= mask - 1;
            bool have1 = (mask != 0);
            int l1 = have1 ? __builtin_ctzll(mask) : l0;
            if (have1) mask &= mask - 1;

            float a0 = __shfl(ampv, l0), d0 = __shfl(dlyv, l0);
            float a1 = __shfl(ampv, l1), d1 = __shfl(dlyv, l1);
            PROCESS(a0, d0);
            if (have1) PROCESS(a1, d1);
        }
    }

    // ---- coalesced float4 writeback (same wave: DS in order, no barrier) ----
    const int n4 = nout / 4;                 // 112 or 64
    float4* out4 = (float4*)(out_rir + (size_t)b * T_LEN + lo);
    out4[lane] = rir4[lane];                 // n4 >= 64 always
    if (lane + 64 < n4) out4[lane + 64] = rir4[lane + 64];
}

extern "C" void kernel_launch(void* const* d_in, const int* in_sizes, int n_in,
                              void* d_out, int out_size, void* d_ws, size_t ws_size,
                              hipStream_t stream) {
    const float* g_in = (const float*)d_in[0];
    const float* W1   = (const float*)d_in[1];
    const float* b1   = (const float*)d_in[2];
    const float* W2   = (const float*)d_in[3];
    const float* b2   = (const float*)d_in[4];
    const float* W3   = (const float*)d_in[5];
    const float* b3   = (const float*)d_in[6];

    const int B = in_sizes[0] / 22;

    float* out_rir    = (float*)d_out;
    float* out_origin = out_rir + (size_t)B * T_LEN;

    dim3 grid(NSLICE, B);   // 54 x 128 = 6912 one-wave blocks
    rir_wave_kernel<<<grid, 64, 0, stream>>>(
        g_in, W1, b1, W2, b2, W3, b3, out_rir, out_origin);
}